// Round 18
// baseline (78.477 us; speedup 1.0000x reference)
//
#include <hip/hip_runtime.h>
#include <math.h>

// ---- workspace layout (float offsets) ----
#define OFF_W1B   0          // bf16 [32 kc][256 n][8 j]
#define OFF_W2A   32768      // bf16 [32 kc][128 o][8 j]
#define OFF_XW1B  49152     // f32 [256]
#define OFF_B2D   49408     // f32 [128]
#define OFF_PT    49536     // f32 [2048]
#define OFF_PE    51584     // f32 [2048]
#define OFF_POUT  53632     // f32 [2048 bt][128 o]   (ends 315776)
#define OFF_MI4   315776    // f32 [32 q][64 g][4]
#define OFF_TEN   323968    // f32 [64]
#define OFF_HH4   324032    // f32 [64 j4][64 g][4]
#define OFF_GI    340416    // f32 [64 g][768]
#define OFF_GH    389568    // f32 [64 g][768]
#define OFF_PLIM  438720    // f32 [32 m][256]
#define OFF_PCOL8 446912    // f32 [256 (m,ch)][256]  (ends 512448)
#define OFF_GMSK  512448    // u32 [2048]
#define OFF_DONE  514496    // u32 [1] last-block ticket

typedef short bf16x8 __attribute__((ext_vector_type(8)));
typedef short s16x4  __attribute__((ext_vector_type(4)));
typedef float f32x4  __attribute__((ext_vector_type(4)));

__device__ __forceinline__ unsigned short f2bf(float f) {
    unsigned u = __builtin_bit_cast(unsigned, f);
    u += 0x7FFFu + ((u >> 16) & 1u);          // RNE
    return (unsigned short)(u >> 16);
}

__device__ __forceinline__ bf16x8 cvt8(float4 a, float4 b) {
    bf16x8 v;
    v[0] = (short)f2bf(a.x); v[1] = (short)f2bf(a.y);
    v[2] = (short)f2bf(a.z); v[3] = (short)f2bf(a.w);
    v[4] = (short)f2bf(b.x); v[5] = (short)f2bf(b.y);
    v[6] = (short)f2bf(b.z); v[7] = (short)f2bf(b.w);
    return v;
}

// ---------------------------------------------------------------------------
// Prep.  Grid 322 x 256.  b<256: pack W1/W2'.  b==256: xw1b/b2d.
// b==257: 32-cell tile bitmask + done ticket.  b 258..321: HH4 gather.
// ---------------------------------------------------------------------------
__global__ __launch_bounds__(256) void k_prep(
    const float* __restrict__ x, const float* __restrict__ hiddens,
    const float* __restrict__ Wa1, const float* __restrict__ ba1,
    const float* __restrict__ Wa2, const float* __restrict__ ba2,
    const float* __restrict__ Wg1, const float* __restrict__ bg1,
    const float* __restrict__ Wg2, const float* __restrict__ bg2,
    const int* __restrict__ msrc, const int* __restrict__ mtgt,
    float* __restrict__ ws)
{
    const int b = blockIdx.x, t = threadIdx.x;
    unsigned short* w1b = (unsigned short*)(ws + OFF_W1B);
    unsigned short* w2a = (unsigned short*)(ws + OFF_W2A);
    if (b < 256) {
        const int n = b;           // t = k index (kc = t>>3, j = t&7)
        const float* row = (n < 128) ? &Wa1[n * 384] : &Wg1[(n - 128) * 384];
        const int kc = t >> 3;
        w1b[(kc * 256 + n) * 8 + (t & 7)] = f2bf(row[128 + t]);
        if (n < 128) {   // W2'[o=n][k=t] : k<128 -> Wa2, else -Wg2
            float w2 = (t < 128) ? Wa2[n * 128 + t] : -Wg2[n * 128 + (t - 128)];
            w2a[(kc * 128 + n) * 8 + (t & 7)] = f2bf(w2);
        }
    } else if (b == 256) {
        const int n = t;
        const float* wr = (n < 128) ? &Wa1[n * 384] : &Wg1[(n - 128) * 384];
        float s = (n < 128) ? ba1[n] : bg1[n - 128];
        for (int j = 0; j < 128; ++j) s = fmaf(x[j], wr[j], s);
        ws[OFF_XW1B + n] = s;
        if (n < 128) ws[OFF_B2D + n] = ba2[n] - bg2[n];
    } else if (b == 257) {
        unsigned* gm = (unsigned*)(ws + OFF_GMSK);
        for (int i = t; i < 2048; i += 256) gm[i] = 0u;
        if (t == 0) ((unsigned*)(ws + OFF_DONE))[0] = 0u;
        __syncthreads();
        if (t < 64) {
            const int cell = (t < 32) ? msrc[t] : mtgt[t - 32];
            atomicOr(&gm[cell >> 5], 1u << (cell & 31));
        }
    } else {
        const int g = b - 258;     // 0..63
        const int cell = (g < 32) ? msrc[g] : mtgt[g - 32];
        ws[OFF_HH4 + (t >> 2) * 256 + g * 4 + (t & 3)] = hiddens[(size_t)cell * 256 + t];
    }
}

// ---------------------------------------------------------------------------
// Main fused kernel (benched-best config).  Grid 2048 x 256 (4 waves), one
// 32-cell tile per block.  launch_bounds(256,2): no VGPR clamp -> no spills.
// Weights: depth-2 scalarized L2 prefetch.  LDS slot swizzle kc^l15.
// ---------------------------------------------------------------------------
__global__ __launch_bounds__(256, 2) void k_main(
    const float* __restrict__ hiddens,
    const int* __restrict__ msrc, const int* __restrict__ mtgt,
    float* __restrict__ ws)
{
    __shared__ __align__(16) short hB[32 * 256];    // 16 KB
    __shared__ __align__(16) short h1B[32 * 256];   // 16 KB
    __shared__ float part[128];
    __shared__ float e_sm[32], t_sm_[32];
    __shared__ int gid_sm[64];

    const int tid  = threadIdx.x;
    const int lane = tid & 63, wid = tid >> 6;       // 4 waves
    const int l15 = lane & 15, l4 = lane >> 4;
    const int bt = blockIdx.x;                       // 32-cell tile id

    if (tid < 64) gid_sm[tid] = (tid < 32) ? msrc[tid] : mtgt[tid - 32];

    const uint4* w1g = (const uint4*)(ws + OFF_W1B);
    const uint4* w2g = (const uint4*)(ws + OFF_W2A);
    const unsigned* gm = (const unsigned*)(ws + OFF_GMSK);

    // ---- stage hiddens tile: thread owns row rc (8 thr/row), 32 cols ----
    {
        const int rc = tid >> 3;
        const float* hsrc = hiddens + (size_t)(bt * 32 + rc) * 256 + (tid & 7) * 32;
        float4 v0 = *(const float4*)(hsrc + 0);
        float4 v1 = *(const float4*)(hsrc + 4);
        float4 v2 = *(const float4*)(hsrc + 8);
        float4 v3 = *(const float4*)(hsrc + 12);
        float4 v4 = *(const float4*)(hsrc + 16);
        float4 v5 = *(const float4*)(hsrc + 20);
        float4 v6 = *(const float4*)(hsrc + 24);
        float4 v7 = *(const float4*)(hsrc + 28);
        const int kc0 = (tid & 7) * 4;
        *(bf16x8*)&hB[rc * 256 + (((kc0 + 0) ^ (rc & 15)) << 3)] = cvt8(v0, v1);
        *(bf16x8*)&hB[rc * 256 + (((kc0 + 1) ^ (rc & 15)) << 3)] = cvt8(v2, v3);
        *(bf16x8*)&hB[rc * 256 + (((kc0 + 2) ^ (rc & 15)) << 3)] = cvt8(v4, v5);
        *(bf16x8*)&hB[rc * 256 + (((kc0 + 3) ^ (rc & 15)) << 3)] = cvt8(v6, v7);
    }
    __syncthreads();   // B0

    // ---- GEMM1: D1[n][c], wave owns 64 n.  Depth-2 scalarized prefetch ----
    const int wb1 = wid * 64 + l15;
    uint4 c0 = w1g[(0 + l4) * 256 + wb1 + 0];
    uint4 c1 = w1g[(0 + l4) * 256 + wb1 + 16];
    uint4 c2 = w1g[(0 + l4) * 256 + wb1 + 32];
    uint4 c3 = w1g[(0 + l4) * 256 + wb1 + 48];
    uint4 p0 = w1g[(4 + l4) * 256 + wb1 + 0];
    uint4 p1 = w1g[(4 + l4) * 256 + wb1 + 16];
    uint4 p2 = w1g[(4 + l4) * 256 + wb1 + 32];
    uint4 p3 = w1g[(4 + l4) * 256 + wb1 + 48];
    uint4 g2c0, g2c1, g2p0, g2p1;

    f32x4 acc[4][2];
#pragma unroll
    for (int q = 0; q < 4; ++q)
#pragma unroll
        for (int ct = 0; ct < 2; ++ct) acc[q][ct] = (f32x4)0.f;

    __builtin_amdgcn_s_setprio(1);
#pragma unroll
    for (int s = 0; s < 8; ++s) {
        uint4 f0, f1, f2, f3;
        if (s < 6) {
            f0 = w1g[((s + 2) * 4 + l4) * 256 + wb1 + 0];
            f1 = w1g[((s + 2) * 4 + l4) * 256 + wb1 + 16];
            f2 = w1g[((s + 2) * 4 + l4) * 256 + wb1 + 32];
            f3 = w1g[((s + 2) * 4 + l4) * 256 + wb1 + 48];
        } else if (s == 6) {
            g2c0 = w2g[(0 + l4) * 128 + wid * 32 + l15];
            g2c1 = w2g[(0 + l4) * 128 + wid * 32 + 16 + l15];
        } else {
            g2p0 = w2g[(4 + l4) * 128 + wid * 32 + l15];
            g2p1 = w2g[(4 + l4) * 128 + wid * 32 + 16 + l15];
        }
        bf16x8 bfr0 = *(const bf16x8*)&hB[(0 * 16 + l15) * 256 + (((s * 4 + l4) ^ l15) << 3)];
        bf16x8 bfr1 = *(const bf16x8*)&hB[(1 * 16 + l15) * 256 + (((s * 4 + l4) ^ l15) << 3)];
        acc[0][0] = __builtin_amdgcn_mfma_f32_16x16x32_bf16(__builtin_bit_cast(bf16x8, c0), bfr0, acc[0][0], 0, 0, 0);
        acc[0][1] = __builtin_amdgcn_mfma_f32_16x16x32_bf16(__builtin_bit_cast(bf16x8, c0), bfr1, acc[0][1], 0, 0, 0);
        acc[1][0] = __builtin_amdgcn_mfma_f32_16x16x32_bf16(__builtin_bit_cast(bf16x8, c1), bfr0, acc[1][0], 0, 0, 0);
        acc[1][1] = __builtin_amdgcn_mfma_f32_16x16x32_bf16(__builtin_bit_cast(bf16x8, c1), bfr1, acc[1][1], 0, 0, 0);
        acc[2][0] = __builtin_amdgcn_mfma_f32_16x16x32_bf16(__builtin_bit_cast(bf16x8, c2), bfr0, acc[2][0], 0, 0, 0);
        acc[2][1] = __builtin_amdgcn_mfma_f32_16x16x32_bf16(__builtin_bit_cast(bf16x8, c2), bfr1, acc[2][1], 0, 0, 0);
        acc[3][0] = __builtin_amdgcn_mfma_f32_16x16x32_bf16(__builtin_bit_cast(bf16x8, c3), bfr0, acc[3][0], 0, 0, 0);
        acc[3][1] = __builtin_amdgcn_mfma_f32_16x16x32_bf16(__builtin_bit_cast(bf16x8, c3), bfr1, acc[3][1], 0, 0, 0);
        c0 = p0; c1 = p1; c2 = p2; c3 = p3;
        if (s < 6) { p0 = f0; p1 = f1; p2 = f2; p3 = f3; }
    }
    __builtin_amdgcn_s_setprio(0);

    // ---- bias + relu -> h1B (bf16, swizzled) ----
#pragma unroll
    for (int nt = 0; nt < 4; ++nt) {
        const int n0 = wid * 64 + nt * 16 + l4 * 4;
        float4 xb = *(const float4*)(ws + OFF_XW1B + n0);
        const float bx[4] = {xb.x, xb.y, xb.z, xb.w};
        const int chunk = n0 >> 3;
        const int off = (l4 & 1) * 4;
#pragma unroll
        for (int ct = 0; ct < 2; ++ct) {
            const int c = ct * 16 + l15;
            s16x4 pk;
#pragma unroll
            for (int r = 0; r < 4; ++r)
                pk[r] = (short)f2bf(fmaxf(acc[nt][ct][r] + bx[r], 0.f));
            *(s16x4*)&h1B[c * 256 + ((chunk ^ l15) << 3) + off] = pk;
        }
    }
    __syncthreads();   // B1: h1B ready

    // ---- GEMM2: D2[o][c], wave owns 32 o ----
    f32x4 acc2[2][2];
#pragma unroll
    for (int ot = 0; ot < 2; ++ot)
#pragma unroll
        for (int ct = 0; ct < 2; ++ct) acc2[ot][ct] = (f32x4)0.f;

    __builtin_amdgcn_s_setprio(1);
#pragma unroll
    for (int s = 0; s < 8; ++s) {
        uint4 f0, f1;
        if (s < 6) {
            f0 = w2g[((s + 2) * 4 + l4) * 128 + wid * 32 + l15];
            f1 = w2g[((s + 2) * 4 + l4) * 128 + wid * 32 + 16 + l15];
        }
        bf16x8 b20 = *(const bf16x8*)&h1B[(0 * 16 + l15) * 256 + (((s * 4 + l4) ^ l15) << 3)];
        bf16x8 b21 = *(const bf16x8*)&h1B[(1 * 16 + l15) * 256 + (((s * 4 + l4) ^ l15) << 3)];
        acc2[0][0] = __builtin_amdgcn_mfma_f32_16x16x32_bf16(__builtin_bit_cast(bf16x8, g2c0), b20, acc2[0][0], 0, 0, 0);
        acc2[0][1] = __builtin_amdgcn_mfma_f32_16x16x32_bf16(__builtin_bit_cast(bf16x8, g2c0), b21, acc2[0][1], 0, 0, 0);
        acc2[1][0] = __builtin_amdgcn_mfma_f32_16x16x32_bf16(__builtin_bit_cast(bf16x8, g2c1), b20, acc2[1][0], 0, 0, 0);
        acc2[1][1] = __builtin_amdgcn_mfma_f32_16x16x32_bf16(__builtin_bit_cast(bf16x8, g2c1), b21, acc2[1][1], 0, 0, 0);
        g2c0 = g2p0; g2c1 = g2p1;
        if (s < 6) { g2p0 = f0; g2p1 = f1; }
    }
    __builtin_amdgcn_s_setprio(0);

    // ---- epilogue ----
    float outv[2][2][4];
#pragma unroll
    for (int ot = 0; ot < 2; ++ot) {
        float4 bd = *(const float4*)(ws + OFF_B2D + wid * 32 + ot * 16 + l4 * 4);
        const float bv[4] = {bd.x, bd.y, bd.z, bd.w};
#pragma unroll
        for (int ct = 0; ct < 2; ++ct)
#pragma unroll
            for (int r = 0; r < 4; ++r)
                outv[ot][ct][r] = acc2[ot][ct][r] + bv[r];
    }

#pragma unroll
    for (int ct = 0; ct < 2; ++ct) {
        float sq = 0.f;
#pragma unroll
        for (int ot = 0; ot < 2; ++ot)
#pragma unroll
            for (int r = 0; r < 4; ++r)
                sq = fmaf(outv[ot][ct][r], outv[ot][ct][r], sq);
        sq += __shfl_xor(sq, 16);
        sq += __shfl_xor(sq, 32);
        if (l4 == 0) part[wid * 32 + ct * 16 + l15] = sq;
    }
    __syncthreads();   // B2

    if (tid < 32) {
        float s = part[tid] + part[32 + tid] + part[64 + tid] + part[96 + tid];
        const float tv = s * (1.f / 128.f);
        const float ev = expf(tv);
        t_sm_[tid] = tv; e_sm[tid] = ev;
        float pt = tv, pe = ev;
        for (int off = 16; off > 0; off >>= 1) {
            pt += __shfl_down(pt, off);
            pe += __shfl_down(pe, off);
        }
        if (tid == 0) { ws[OFF_PT + bt] = pt; ws[OFF_PE + bt] = pe; }
        unsigned m = gm[bt];
        while (m) {
            const int g = __builtin_ctz(m); m &= m - 1;
            const int cg = gid_sm[g];
            if ((cg >> 5) == bt && (cg & 31) == tid) ws[OFF_TEN + g] = tv;
        }
    }
    __syncthreads();   // B3

    {   // weighted-out partial: wave owns 32 o over 32 cells
        float p[2][4];
#pragma unroll
        for (int ot = 0; ot < 2; ++ot)
#pragma unroll
            for (int r = 0; r < 4; ++r) {
                float s = e_sm[l15] * outv[ot][0][r];
                s = fmaf(e_sm[16 + l15], outv[ot][1][r], s);
                p[ot][r] = s;
            }
#pragma unroll
        for (int ot = 0; ot < 2; ++ot)
#pragma unroll
            for (int r = 0; r < 4; ++r) {
                p[ot][r] += __shfl_xor(p[ot][r], 1);
                p[ot][r] += __shfl_xor(p[ot][r], 2);
                p[ot][r] += __shfl_xor(p[ot][r], 4);
                p[ot][r] += __shfl_xor(p[ot][r], 8);
            }
        if (l15 == 0) {
#pragma unroll
            for (int ot = 0; ot < 2; ++ot)
                *(float4*)(ws + OFF_POUT + (size_t)bt * 128 + wid * 32 + ot * 16 + l4 * 4) =
                    make_float4(p[ot][0], p[ot][1], p[ot][2], p[ot][3]);
        }
    }
    {   // gathered mem_in rows from registers
        unsigned m = gm[bt];
        while (m) {
            const int g = __builtin_ctz(m); m &= m - 1;
            const int cg = gid_sm[g];
            if ((cg >> 5) != bt) continue;
            const int c = cg & 31;
            if ((c & 15) == l15) {
                const int ct = c >> 4;
#pragma unroll
                for (int ot = 0; ot < 2; ++ot)
                    *(float4*)(ws + OFF_MI4 + (wid * 8 + ot * 4 + l4) * 256 + g * 4) =
                        make_float4(outv[ot][ct][0], outv[ot][ct][1],
                                    outv[ot][ct][2], outv[ot][ct][3]);
            }
        }
    }
}

// ---------------------------------------------------------------------------
// Tail1 + combined_out.  Grid 256 x 256.
// Blocks 0..191: gi/gh gate rows.  Blocks 192..255: combined_out columns.
// ---------------------------------------------------------------------------
__global__ __launch_bounds__(256) void k_tail1(
    const float* __restrict__ W_ih, const float* __restrict__ W_hh,
    const float* __restrict__ b_ih, const float* __restrict__ b_hh,
    float* __restrict__ ws, float* __restrict__ out)
{
    __shared__ float red[256];
    const int b = blockIdx.x, t = threadIdx.x;
    if (b < 192) {
        const int lane = t & 63;
        const int w    = t >> 6;
        const int row  = __builtin_amdgcn_readfirstlane(b * 4 + w);
        const float* mi4 = ws + OFF_MI4;
        const float* hh4 = ws + OFF_HH4;

        const float* wi = W_ih + row * 129;
        float gi = b_ih[row];
#pragma unroll 8
        for (int q = 0; q < 32; ++q) {
            float4 a = *(const float4*)(mi4 + q * 256 + lane * 4);
            gi = fmaf(wi[4 * q + 0], a.x, gi);
            gi = fmaf(wi[4 * q + 1], a.y, gi);
            gi = fmaf(wi[4 * q + 2], a.z, gi);
            gi = fmaf(wi[4 * q + 3], a.w, gi);
        }
        gi = fmaf(ws[OFF_TEN + lane], wi[128], gi);

        const float* wh = W_hh + (size_t)row * 256;
        float gh = b_hh[row];
#pragma unroll 8
        for (int q = 0; q < 64; ++q) {
            float4 a = *(const float4*)(hh4 + q * 256 + lane * 4);
            float4 bb = *(const float4*)(wh + 4 * q);
            gh = fmaf(bb.x, a.x, gh);
            gh = fmaf(bb.y, a.y, gh);
            gh = fmaf(bb.z, a.z, gh);
            gh = fmaf(bb.w, a.w, gh);
        }
        ws[OFF_GI + lane * 768 + row] = gi;
        ws[OFF_GH + lane * 768 + row] = gh;
    } else {
#pragma unroll
        for (int cc = 0; cc < 2; ++cc) {
            const int col = (b - 192) * 2 + cc;
            float so = 0.f, se = 0.f;
            for (int i = t; i < 2048; i += 256) {
                so += ws[OFF_POUT + (size_t)i * 128 + col];
                se += ws[OFF_PE + i];
            }
            red[t] = so; __syncthreads();
            for (int s = 128; s > 0; s >>= 1) { if (t < s) red[t] += red[t + s]; __syncthreads(); }
            const float SO = red[0]; __syncthreads();
            red[t] = se; __syncthreads();
            for (int s = 128; s > 0; s >>= 1) { if (t < s) red[t] += red[t + s]; __syncthreads(); }
            if (t == 0) out[col] = SO / red[0];
            __syncthreads();
        }
    }
}

// ---------------------------------------------------------------------------
// Morph (+GRU elementwise + nat) + last-block avg_tension.  Grid 256 x 256:
// block = (m = blk>>3, ch = blk&7).  After writing partials, thread 0 takes
// a device-scope ticket; the 256th arrival (necessarily last) computes
// avg_tension.  No spinning, no ordering assumption.
// ---------------------------------------------------------------------------
__global__ __launch_bounds__(256) void k_morph(
    const float* __restrict__ morph_w, const float* __restrict__ nat_w,
    const int* __restrict__ step, float* __restrict__ ws,
    float* __restrict__ out)
{
    __shared__ float wsm[32 * 264];
    __shared__ float hd0[256], hd1[256];
    __shared__ float hs[256], ht[256];
    __shared__ float red[256];
    __shared__ int is_last;
    const int blk = blockIdx.x, t = threadIdx.x;
    const int m = blk >> 3, ch = blk & 7;
    const float* wm = morph_w + (size_t)m * 65536 + (size_t)ch * 32 * 256;
    {
        const int r = t >> 3, c0 = (t & 7) * 32;
#pragma unroll
        for (int it = 0; it < 8; ++it)
            *(float4*)&wsm[r * 264 + c0 + it * 4] = *(const float4*)(wm + r * 256 + c0 + it * 4);
    }
#pragma unroll
    for (int h = 0; h < 2; ++h) {
        const int g = h * 32 + m;
        const float i_r = ws[OFF_GI + g * 768 + t];
        const float i_z = ws[OFF_GI + g * 768 + 256 + t];
        const float i_n = ws[OFF_GI + g * 768 + 512 + t];
        const float h_r = ws[OFF_GH + g * 768 + t];
        const float h_z = ws[OFF_GH + g * 768 + 256 + t];
        const float h_n = ws[OFF_GH + g * 768 + 512 + t];
        const float hv  = ws[OFF_HH4 + (t >> 2) * 256 + g * 4 + (t & 3)];
        const float r  = 1.f / (1.f + expf(-(i_r + h_r)));
        const float z  = 1.f / (1.f + expf(-(i_z + h_z)));
        const float nn = tanhf(i_n + r * h_n);
        const float hid = (1.f - z) * nn + z * hv;
        if (h == 0) hd0[t] = hid; else hd1[t] = hid;
    }
    __syncthreads();

    float hn0, hn1;
    if (step[0] % 3 == 0) {
        const float4* wr = (const float4*)(nat_w + (size_t)t * 256);
        float s0 = 0.f, s1 = 0.f;
        for (int q = 0; q < 64; ++q) {
            float4 wq = wr[q];
            s0 = fmaf(wq.x, hd0[4 * q + 0], s0); s1 = fmaf(wq.x, hd1[4 * q + 0], s1);
            s0 = fmaf(wq.y, hd0[4 * q + 1], s0); s1 = fmaf(wq.y, hd1[4 * q + 1], s1);
            s0 = fmaf(wq.z, hd0[4 * q + 2], s0); s1 = fmaf(wq.z, hd1[4 * q + 2], s1);
            s0 = fmaf(wq.w, hd0[4 * q + 3], s0); s1 = fmaf(wq.w, hd1[4 * q + 3], s1);
        }
        hn0 = s0; hn1 = s1;
    } else {
        hn0 = hd0[t]; hn1 = hd1[t];
    }
    hs[t] = hn0; ht[t] = hn1;
    __syncthreads();

    {   // limit rows i = ch*32 + il (full dot over j)
        const int il = t >> 3, jc = t & 7;
        float L = 0.f;
#pragma unroll 8
        for (int jj = 0; jj < 32; ++jj) {
            const int j = jc + 8 * jj;
            L = fmaf(wsm[il * 264 + j], hs[j], L);
        }
        L += __shfl_down(L, 4);
        L += __shfl_down(L, 2);
        L += __shfl_down(L, 1);
        if (jc == 0) ws[OFF_PLIM + m * 256 + ch * 32 + il] = L;
    }
    {   // colimit partial
        float C = 0.f;
#pragma unroll 8
        for (int r = 0; r < 32; ++r)
            C = fmaf(wsm[r * 264 + t], ht[ch * 32 + r], C);
        ws[OFF_PCOL8 + blk * 256 + t] = C;
    }

    // ---- last-block ticket: 256th arrival computes avg_tension ----
    __syncthreads();
    if (t == 0) {
        unsigned old = __hip_atomic_fetch_add((unsigned*)(ws + OFF_DONE), 1u,
                                              __ATOMIC_ACQ_REL, __HIP_MEMORY_SCOPE_AGENT);
        is_last = (old == 255u);
    }
    __syncthreads();
    if (is_last) {
        float pt = 0.f;
        for (int i = t; i < 2048; i += 256) pt += ws[OFF_PT + i];
        float L = 0.f, C = 0.f;
        for (int mm = 0; mm < 32; ++mm) L += ws[OFF_PLIM + mm * 256 + t];
        for (int mc = 0; mc < 256; ++mc) C += ws[OFF_PCOL8 + mc * 256 + t];
        const float d = (L - C) * (1.f / 32.f);
        red[t] = d * d; __syncthreads();
        for (int s = 128; s > 0; s >>= 1) { if (t < s) red[t] += red[t + s]; __syncthreads(); }
        const float cat = red[0] * (1.f / 256.f); __syncthreads();
        red[t] = pt; __syncthreads();
        for (int s = 128; s > 0; s >>= 1) { if (t < s) red[t] += red[t + s]; __syncthreads(); }
        if (t == 0) out[128] = red[0] * (1.f / 65536.f) + 0.1f * cat;
    }
}

// ---------------------------------------------------------------------------
extern "C" void kernel_launch(void* const* d_in, const int* in_sizes, int n_in,
                              void* d_out, int out_size, void* d_ws, size_t ws_size,
                              hipStream_t stream)
{
    const float* x     = (const float*)d_in[0];
    const float* hidd  = (const float*)d_in[1];
    const float* Wa1   = (const float*)d_in[2];
    const float* ba1   = (const float*)d_in[3];
    const float* Wa2   = (const float*)d_in[4];
    const float* ba2   = (const float*)d_in[5];
    const float* Wg1   = (const float*)d_in[6];
    const float* bg1   = (const float*)d_in[7];
    const float* Wg2   = (const float*)d_in[8];
    const float* bg2   = (const float*)d_in[9];
    const float* W_ih  = (const float*)d_in[10];
    const float* W_hh  = (const float*)d_in[11];
    const float* b_ih  = (const float*)d_in[12];
    const float* b_hh  = (const float*)d_in[13];
    const float* nat_w = (const float*)d_in[14];
    const float* mw    = (const float*)d_in[15];
    const int*   msrc  = (const int*)d_in[16];
    const int*   mtgt  = (const int*)d_in[17];
    const int*   step  = (const int*)d_in[18];

    float* out = (float*)d_out;
    float* ws  = (float*)d_ws;

    k_prep <<<322, 256, 0, stream>>>(x, hidd, Wa1, ba1, Wa2, ba2, Wg1, bg1, Wg2, bg2, msrc, mtgt, ws);
    k_main <<<2048, 256, 0, stream>>>(hidd, msrc, mtgt, ws);
    k_tail1<<<256, 256, 0, stream>>>(W_ih, W_hh, b_ih, b_hh, ws, out);
    k_morph<<<256, 256, 0, stream>>>(mw, nat_w, step, ws, out);
}

// Round 19
// 74.007 us; speedup vs baseline: 1.0604x; 1.0604x over previous
//
#include <hip/hip_runtime.h>
#include <math.h>

// ---- workspace layout (float offsets) ----
#define OFF_W1B   0          // bf16 [32 kc][256 n][8 j]
#define OFF_W2A   32768      // bf16 [32 kc][128 o][8 j]
#define OFF_XW1B  49152     // f32 [256]
#define OFF_B2D   49408     // f32 [128]
#define OFF_PT    49536     // f32 [2048]
#define OFF_PE    51584     // f32 [2048]
#define OFF_POUT  53632     // f32 [2048 bt][128 o]   (ends 315776)
#define OFF_MI4   315776    // f32 [32 q][64 g][4]
#define OFF_TEN   323968    // f32 [64]
#define OFF_HH4   324032    // f32 [64 j4][64 g][4]
#define OFF_GI    340416    // f32 [64 g][768]
#define OFF_GH    389568    // f32 [64 g][768]
#define OFF_PLIM  438720    // f32 [32 m][256]
#define OFF_PCOL8 446912    // f32 [256 (m,ch)][256]  (ends 512448)
#define OFF_GMSK  512448    // u32 [2048]

typedef short bf16x8 __attribute__((ext_vector_type(8)));
typedef short s16x4  __attribute__((ext_vector_type(4)));
typedef float f32x4  __attribute__((ext_vector_type(4)));

__device__ __forceinline__ unsigned short f2bf(float f) {
    unsigned u = __builtin_bit_cast(unsigned, f);
    u += 0x7FFFu + ((u >> 16) & 1u);          // RNE
    return (unsigned short)(u >> 16);
}

__device__ __forceinline__ bf16x8 cvt8(float4 a, float4 b) {
    bf16x8 v;
    v[0] = (short)f2bf(a.x); v[1] = (short)f2bf(a.y);
    v[2] = (short)f2bf(a.z); v[3] = (short)f2bf(a.w);
    v[4] = (short)f2bf(b.x); v[5] = (short)f2bf(b.y);
    v[6] = (short)f2bf(b.z); v[7] = (short)f2bf(b.w);
    return v;
}

// ---------------------------------------------------------------------------
// Prep.  Grid 322 x 256.  b<256: pack W1/W2'.  b==256: xw1b/b2d.
// b==257: 32-cell tile bitmask.  b 258..321: HH4 gather.
// ---------------------------------------------------------------------------
__global__ __launch_bounds__(256) void k_prep(
    const float* __restrict__ x, const float* __restrict__ hiddens,
    const float* __restrict__ Wa1, const float* __restrict__ ba1,
    const float* __restrict__ Wa2, const float* __restrict__ ba2,
    const float* __restrict__ Wg1, const float* __restrict__ bg1,
    const float* __restrict__ Wg2, const float* __restrict__ bg2,
    const int* __restrict__ msrc, const int* __restrict__ mtgt,
    float* __restrict__ ws)
{
    const int b = blockIdx.x, t = threadIdx.x;
    unsigned short* w1b = (unsigned short*)(ws + OFF_W1B);
    unsigned short* w2a = (unsigned short*)(ws + OFF_W2A);
    if (b < 256) {
        const int n = b;           // t = k index (kc = t>>3, j = t&7)
        const float* row = (n < 128) ? &Wa1[n * 384] : &Wg1[(n - 128) * 384];
        const int kc = t >> 3;
        w1b[(kc * 256 + n) * 8 + (t & 7)] = f2bf(row[128 + t]);
        if (n < 128) {   // W2'[o=n][k=t] : k<128 -> Wa2, else -Wg2
            float w2 = (t < 128) ? Wa2[n * 128 + t] : -Wg2[n * 128 + (t - 128)];
            w2a[(kc * 128 + n) * 8 + (t & 7)] = f2bf(w2);
        }
    } else if (b == 256) {
        const int n = t;
        const float* wr = (n < 128) ? &Wa1[n * 384] : &Wg1[(n - 128) * 384];
        float s = (n < 128) ? ba1[n] : bg1[n - 128];
        for (int j = 0; j < 128; ++j) s = fmaf(x[j], wr[j], s);
        ws[OFF_XW1B + n] = s;
        if (n < 128) ws[OFF_B2D + n] = ba2[n] - bg2[n];
    } else if (b == 257) {
        unsigned* gm = (unsigned*)(ws + OFF_GMSK);
        for (int i = t; i < 2048; i += 256) gm[i] = 0u;
        __syncthreads();
        if (t < 64) {
            const int cell = (t < 32) ? msrc[t] : mtgt[t - 32];
            atomicOr(&gm[cell >> 5], 1u << (cell & 31));
        }
    } else {
        const int g = b - 258;     // 0..63
        const int cell = (g < 32) ? msrc[g] : mtgt[g - 32];
        ws[OFF_HH4 + (t >> 2) * 256 + g * 4 + (t & 3)] = hiddens[(size_t)cell * 256 + t];
    }
}

// ---------------------------------------------------------------------------
// Main fused kernel (benched-best config).  Grid 2048 x 256 (4 waves), one
// 32-cell tile per block.  launch_bounds(256,2): no VGPR clamp -> no spills.
// Weights: depth-2 scalarized L2 prefetch.  LDS slot swizzle kc^l15.
// ---------------------------------------------------------------------------
__global__ __launch_bounds__(256, 2) void k_main(
    const float* __restrict__ hiddens,
    const int* __restrict__ msrc, const int* __restrict__ mtgt,
    float* __restrict__ ws)
{
    __shared__ __align__(16) short hB[32 * 256];    // 16 KB
    __shared__ __align__(16) short h1B[32 * 256];   // 16 KB
    __shared__ float part[128];
    __shared__ float e_sm[32], t_sm_[32];
    __shared__ int gid_sm[64];

    const int tid  = threadIdx.x;
    const int lane = tid & 63, wid = tid >> 6;       // 4 waves
    const int l15 = lane & 15, l4 = lane >> 4;
    const int bt = blockIdx.x;                       // 32-cell tile id

    if (tid < 64) gid_sm[tid] = (tid < 32) ? msrc[tid] : mtgt[tid - 32];

    const uint4* w1g = (const uint4*)(ws + OFF_W1B);
    const uint4* w2g = (const uint4*)(ws + OFF_W2A);
    const unsigned* gm = (const unsigned*)(ws + OFF_GMSK);

    // ---- stage hiddens tile: thread owns row rc (8 thr/row), 32 cols ----
    {
        const int rc = tid >> 3;
        const float* hsrc = hiddens + (size_t)(bt * 32 + rc) * 256 + (tid & 7) * 32;
        float4 v0 = *(const float4*)(hsrc + 0);
        float4 v1 = *(const float4*)(hsrc + 4);
        float4 v2 = *(const float4*)(hsrc + 8);
        float4 v3 = *(const float4*)(hsrc + 12);
        float4 v4 = *(const float4*)(hsrc + 16);
        float4 v5 = *(const float4*)(hsrc + 20);
        float4 v6 = *(const float4*)(hsrc + 24);
        float4 v7 = *(const float4*)(hsrc + 28);
        const int kc0 = (tid & 7) * 4;
        *(bf16x8*)&hB[rc * 256 + (((kc0 + 0) ^ (rc & 15)) << 3)] = cvt8(v0, v1);
        *(bf16x8*)&hB[rc * 256 + (((kc0 + 1) ^ (rc & 15)) << 3)] = cvt8(v2, v3);
        *(bf16x8*)&hB[rc * 256 + (((kc0 + 2) ^ (rc & 15)) << 3)] = cvt8(v4, v5);
        *(bf16x8*)&hB[rc * 256 + (((kc0 + 3) ^ (rc & 15)) << 3)] = cvt8(v6, v7);
    }
    __syncthreads();   // B0

    // ---- GEMM1: D1[n][c], wave owns 64 n.  Depth-2 scalarized prefetch ----
    const int wb1 = wid * 64 + l15;
    uint4 c0 = w1g[(0 + l4) * 256 + wb1 + 0];
    uint4 c1 = w1g[(0 + l4) * 256 + wb1 + 16];
    uint4 c2 = w1g[(0 + l4) * 256 + wb1 + 32];
    uint4 c3 = w1g[(0 + l4) * 256 + wb1 + 48];
    uint4 p0 = w1g[(4 + l4) * 256 + wb1 + 0];
    uint4 p1 = w1g[(4 + l4) * 256 + wb1 + 16];
    uint4 p2 = w1g[(4 + l4) * 256 + wb1 + 32];
    uint4 p3 = w1g[(4 + l4) * 256 + wb1 + 48];
    uint4 g2c0, g2c1, g2p0, g2p1;

    f32x4 acc[4][2];
#pragma unroll
    for (int q = 0; q < 4; ++q)
#pragma unroll
        for (int ct = 0; ct < 2; ++ct) acc[q][ct] = (f32x4)0.f;

    __builtin_amdgcn_s_setprio(1);
#pragma unroll
    for (int s = 0; s < 8; ++s) {
        uint4 f0, f1, f2, f3;
        if (s < 6) {
            f0 = w1g[((s + 2) * 4 + l4) * 256 + wb1 + 0];
            f1 = w1g[((s + 2) * 4 + l4) * 256 + wb1 + 16];
            f2 = w1g[((s + 2) * 4 + l4) * 256 + wb1 + 32];
            f3 = w1g[((s + 2) * 4 + l4) * 256 + wb1 + 48];
        } else if (s == 6) {
            g2c0 = w2g[(0 + l4) * 128 + wid * 32 + l15];
            g2c1 = w2g[(0 + l4) * 128 + wid * 32 + 16 + l15];
        } else {
            g2p0 = w2g[(4 + l4) * 128 + wid * 32 + l15];
            g2p1 = w2g[(4 + l4) * 128 + wid * 32 + 16 + l15];
        }
        bf16x8 bfr0 = *(const bf16x8*)&hB[(0 * 16 + l15) * 256 + (((s * 4 + l4) ^ l15) << 3)];
        bf16x8 bfr1 = *(const bf16x8*)&hB[(1 * 16 + l15) * 256 + (((s * 4 + l4) ^ l15) << 3)];
        acc[0][0] = __builtin_amdgcn_mfma_f32_16x16x32_bf16(__builtin_bit_cast(bf16x8, c0), bfr0, acc[0][0], 0, 0, 0);
        acc[0][1] = __builtin_amdgcn_mfma_f32_16x16x32_bf16(__builtin_bit_cast(bf16x8, c0), bfr1, acc[0][1], 0, 0, 0);
        acc[1][0] = __builtin_amdgcn_mfma_f32_16x16x32_bf16(__builtin_bit_cast(bf16x8, c1), bfr0, acc[1][0], 0, 0, 0);
        acc[1][1] = __builtin_amdgcn_mfma_f32_16x16x32_bf16(__builtin_bit_cast(bf16x8, c1), bfr1, acc[1][1], 0, 0, 0);
        acc[2][0] = __builtin_amdgcn_mfma_f32_16x16x32_bf16(__builtin_bit_cast(bf16x8, c2), bfr0, acc[2][0], 0, 0, 0);
        acc[2][1] = __builtin_amdgcn_mfma_f32_16x16x32_bf16(__builtin_bit_cast(bf16x8, c2), bfr1, acc[2][1], 0, 0, 0);
        acc[3][0] = __builtin_amdgcn_mfma_f32_16x16x32_bf16(__builtin_bit_cast(bf16x8, c3), bfr0, acc[3][0], 0, 0, 0);
        acc[3][1] = __builtin_amdgcn_mfma_f32_16x16x32_bf16(__builtin_bit_cast(bf16x8, c3), bfr1, acc[3][1], 0, 0, 0);
        c0 = p0; c1 = p1; c2 = p2; c3 = p3;
        if (s < 6) { p0 = f0; p1 = f1; p2 = f2; p3 = f3; }
    }
    __builtin_amdgcn_s_setprio(0);

    // ---- bias + relu -> h1B (bf16, swizzled) ----
#pragma unroll
    for (int nt = 0; nt < 4; ++nt) {
        const int n0 = wid * 64 + nt * 16 + l4 * 4;
        float4 xb = *(const float4*)(ws + OFF_XW1B + n0);
        const float bx[4] = {xb.x, xb.y, xb.z, xb.w};
        const int chunk = n0 >> 3;
        const int off = (l4 & 1) * 4;
#pragma unroll
        for (int ct = 0; ct < 2; ++ct) {
            const int c = ct * 16 + l15;
            s16x4 pk;
#pragma unroll
            for (int r = 0; r < 4; ++r)
                pk[r] = (short)f2bf(fmaxf(acc[nt][ct][r] + bx[r], 0.f));
            *(s16x4*)&h1B[c * 256 + ((chunk ^ l15) << 3) + off] = pk;
        }
    }
    __syncthreads();   // B1: h1B ready

    // ---- GEMM2: D2[o][c], wave owns 32 o ----
    f32x4 acc2[2][2];
#pragma unroll
    for (int ot = 0; ot < 2; ++ot)
#pragma unroll
        for (int ct = 0; ct < 2; ++ct) acc2[ot][ct] = (f32x4)0.f;

    __builtin_amdgcn_s_setprio(1);
#pragma unroll
    for (int s = 0; s < 8; ++s) {
        uint4 f0, f1;
        if (s < 6) {
            f0 = w2g[((s + 2) * 4 + l4) * 128 + wid * 32 + l15];
            f1 = w2g[((s + 2) * 4 + l4) * 128 + wid * 32 + 16 + l15];
        }
        bf16x8 b20 = *(const bf16x8*)&h1B[(0 * 16 + l15) * 256 + (((s * 4 + l4) ^ l15) << 3)];
        bf16x8 b21 = *(const bf16x8*)&h1B[(1 * 16 + l15) * 256 + (((s * 4 + l4) ^ l15) << 3)];
        acc2[0][0] = __builtin_amdgcn_mfma_f32_16x16x32_bf16(__builtin_bit_cast(bf16x8, g2c0), b20, acc2[0][0], 0, 0, 0);
        acc2[0][1] = __builtin_amdgcn_mfma_f32_16x16x32_bf16(__builtin_bit_cast(bf16x8, g2c0), b21, acc2[0][1], 0, 0, 0);
        acc2[1][0] = __builtin_amdgcn_mfma_f32_16x16x32_bf16(__builtin_bit_cast(bf16x8, g2c1), b20, acc2[1][0], 0, 0, 0);
        acc2[1][1] = __builtin_amdgcn_mfma_f32_16x16x32_bf16(__builtin_bit_cast(bf16x8, g2c1), b21, acc2[1][1], 0, 0, 0);
        g2c0 = g2p0; g2c1 = g2p1;
        if (s < 6) { g2p0 = f0; g2p1 = f1; }
    }
    __builtin_amdgcn_s_setprio(0);

    // ---- epilogue ----
    float outv[2][2][4];
#pragma unroll
    for (int ot = 0; ot < 2; ++ot) {
        float4 bd = *(const float4*)(ws + OFF_B2D + wid * 32 + ot * 16 + l4 * 4);
        const float bv[4] = {bd.x, bd.y, bd.z, bd.w};
#pragma unroll
        for (int ct = 0; ct < 2; ++ct)
#pragma unroll
            for (int r = 0; r < 4; ++r)
                outv[ot][ct][r] = acc2[ot][ct][r] + bv[r];
    }

#pragma unroll
    for (int ct = 0; ct < 2; ++ct) {
        float sq = 0.f;
#pragma unroll
        for (int ot = 0; ot < 2; ++ot)
#pragma unroll
            for (int r = 0; r < 4; ++r)
                sq = fmaf(outv[ot][ct][r], outv[ot][ct][r], sq);
        sq += __shfl_xor(sq, 16);
        sq += __shfl_xor(sq, 32);
        if (l4 == 0) part[wid * 32 + ct * 16 + l15] = sq;
    }
    __syncthreads();   // B2

    if (tid < 32) {
        float s = part[tid] + part[32 + tid] + part[64 + tid] + part[96 + tid];
        const float tv = s * (1.f / 128.f);
        const float ev = expf(tv);
        t_sm_[tid] = tv; e_sm[tid] = ev;
        float pt = tv, pe = ev;
        for (int off = 16; off > 0; off >>= 1) {
            pt += __shfl_down(pt, off);
            pe += __shfl_down(pe, off);
        }
        if (tid == 0) { ws[OFF_PT + bt] = pt; ws[OFF_PE + bt] = pe; }
        unsigned m = gm[bt];
        while (m) {
            const int g = __builtin_ctz(m); m &= m - 1;
            const int cg = gid_sm[g];
            if ((cg >> 5) == bt && (cg & 31) == tid) ws[OFF_TEN + g] = tv;
        }
    }
    __syncthreads();   // B3

    {   // weighted-out partial: wave owns 32 o over 32 cells
        float p[2][4];
#pragma unroll
        for (int ot = 0; ot < 2; ++ot)
#pragma unroll
            for (int r = 0; r < 4; ++r) {
                float s = e_sm[l15] * outv[ot][0][r];
                s = fmaf(e_sm[16 + l15], outv[ot][1][r], s);
                p[ot][r] = s;
            }
#pragma unroll
        for (int ot = 0; ot < 2; ++ot)
#pragma unroll
            for (int r = 0; r < 4; ++r) {
                p[ot][r] += __shfl_xor(p[ot][r], 1);
                p[ot][r] += __shfl_xor(p[ot][r], 2);
                p[ot][r] += __shfl_xor(p[ot][r], 4);
                p[ot][r] += __shfl_xor(p[ot][r], 8);
            }
        if (l15 == 0) {
#pragma unroll
            for (int ot = 0; ot < 2; ++ot)
                *(float4*)(ws + OFF_POUT + (size_t)bt * 128 + wid * 32 + ot * 16 + l4 * 4) =
                    make_float4(p[ot][0], p[ot][1], p[ot][2], p[ot][3]);
        }
    }
    {   // gathered mem_in rows from registers
        unsigned m = gm[bt];
        while (m) {
            const int g = __builtin_ctz(m); m &= m - 1;
            const int cg = gid_sm[g];
            if ((cg >> 5) != bt) continue;
            const int c = cg & 31;
            if ((c & 15) == l15) {
                const int ct = c >> 4;
#pragma unroll
                for (int ot = 0; ot < 2; ++ot)
                    *(float4*)(ws + OFF_MI4 + (wid * 8 + ot * 4 + l4) * 256 + g * 4) =
                        make_float4(outv[ot][ct][0], outv[ot][ct][1],
                                    outv[ot][ct][2], outv[ot][ct][3]);
            }
        }
    }
}

// ---------------------------------------------------------------------------
// Tail1 + combined_out.  Grid 256 x 256.
// Blocks 0..191: gi/gh gate rows (wave = row, lane = cell).
// Blocks 192..255: combined_out columns (2 per block) -- independent work,
// runs concurrently with the GRU-gate blocks (no barrier needed).
// ---------------------------------------------------------------------------
__global__ __launch_bounds__(256) void k_tail1(
    const float* __restrict__ W_ih, const float* __restrict__ W_hh,
    const float* __restrict__ b_ih, const float* __restrict__ b_hh,
    float* __restrict__ ws, float* __restrict__ out)
{
    __shared__ float red[256];
    const int b = blockIdx.x, t = threadIdx.x;
    if (b < 192) {
        const int lane = t & 63;
        const int w    = t >> 6;
        const int row  = __builtin_amdgcn_readfirstlane(b * 4 + w);
        const float* mi4 = ws + OFF_MI4;
        const float* hh4 = ws + OFF_HH4;

        const float* wi = W_ih + row * 129;
        float gi = b_ih[row];
#pragma unroll 8
        for (int q = 0; q < 32; ++q) {
            float4 a = *(const float4*)(mi4 + q * 256 + lane * 4);
            gi = fmaf(wi[4 * q + 0], a.x, gi);
            gi = fmaf(wi[4 * q + 1], a.y, gi);
            gi = fmaf(wi[4 * q + 2], a.z, gi);
            gi = fmaf(wi[4 * q + 3], a.w, gi);
        }
        gi = fmaf(ws[OFF_TEN + lane], wi[128], gi);

        const float* wh = W_hh + (size_t)row * 256;
        float gh = b_hh[row];
#pragma unroll 8
        for (int q = 0; q < 64; ++q) {
            float4 a = *(const float4*)(hh4 + q * 256 + lane * 4);
            float4 bb = *(const float4*)(wh + 4 * q);
            gh = fmaf(bb.x, a.x, gh);
            gh = fmaf(bb.y, a.y, gh);
            gh = fmaf(bb.z, a.z, gh);
            gh = fmaf(bb.w, a.w, gh);
        }
        ws[OFF_GI + lane * 768 + row] = gi;
        ws[OFF_GH + lane * 768 + row] = gh;
    } else {
#pragma unroll
        for (int cc = 0; cc < 2; ++cc) {
            const int col = (b - 192) * 2 + cc;
            float so = 0.f, se = 0.f;
            for (int i = t; i < 2048; i += 256) {
                so += ws[OFF_POUT + (size_t)i * 128 + col];
                se += ws[OFF_PE + i];
            }
            red[t] = so; __syncthreads();
            for (int s = 128; s > 0; s >>= 1) { if (t < s) red[t] += red[t + s]; __syncthreads(); }
            const float SO = red[0]; __syncthreads();
            red[t] = se; __syncthreads();
            for (int s = 128; s > 0; s >>= 1) { if (t < s) red[t] += red[t + s]; __syncthreads(); }
            if (t == 0) out[col] = SO / red[0];
            __syncthreads();
        }
    }
}

// ---------------------------------------------------------------------------
// Morph (+inline GRU elementwise + nat for its 2 cells).  Grid 256 x 256:
// block = (m = blk>>3, ch = blk&7).
// ---------------------------------------------------------------------------
__global__ __launch_bounds__(256) void k_morph(
    const float* __restrict__ morph_w, const float* __restrict__ nat_w,
    const int* __restrict__ step, float* __restrict__ ws)
{
    __shared__ float wsm[32 * 264];
    __shared__ float hd0[256], hd1[256];
    __shared__ float hs[256], ht[256];
    const int blk = blockIdx.x, t = threadIdx.x;
    const int m = blk >> 3, ch = blk & 7;
    const float* wm = morph_w + (size_t)m * 65536 + (size_t)ch * 32 * 256;
    {
        const int r = t >> 3, c0 = (t & 7) * 32;
#pragma unroll
        for (int it = 0; it < 8; ++it)
            *(float4*)&wsm[r * 264 + c0 + it * 4] = *(const float4*)(wm + r * 256 + c0 + it * 4);
    }
#pragma unroll
    for (int h = 0; h < 2; ++h) {
        const int g = h * 32 + m;
        const float i_r = ws[OFF_GI + g * 768 + t];
        const float i_z = ws[OFF_GI + g * 768 + 256 + t];
        const float i_n = ws[OFF_GI + g * 768 + 512 + t];
        const float h_r = ws[OFF_GH + g * 768 + t];
        const float h_z = ws[OFF_GH + g * 768 + 256 + t];
        const float h_n = ws[OFF_GH + g * 768 + 512 + t];
        const float hv  = ws[OFF_HH4 + (t >> 2) * 256 + g * 4 + (t & 3)];
        const float r  = 1.f / (1.f + expf(-(i_r + h_r)));
        const float z  = 1.f / (1.f + expf(-(i_z + h_z)));
        const float nn = tanhf(i_n + r * h_n);
        const float hid = (1.f - z) * nn + z * hv;
        if (h == 0) hd0[t] = hid; else hd1[t] = hid;
    }
    __syncthreads();

    float hn0, hn1;
    if (step[0] % 3 == 0) {
        const float4* wr = (const float4*)(nat_w + (size_t)t * 256);
        float s0 = 0.f, s1 = 0.f;
        for (int q = 0; q < 64; ++q) {
            float4 wq = wr[q];
            s0 = fmaf(wq.x, hd0[4 * q + 0], s0); s1 = fmaf(wq.x, hd1[4 * q + 0], s1);
            s0 = fmaf(wq.y, hd0[4 * q + 1], s0); s1 = fmaf(wq.y, hd1[4 * q + 1], s1);
            s0 = fmaf(wq.z, hd0[4 * q + 2], s0); s1 = fmaf(wq.z, hd1[4 * q + 2], s1);
            s0 = fmaf(wq.w, hd0[4 * q + 3], s0); s1 = fmaf(wq.w, hd1[4 * q + 3], s1);
        }
        hn0 = s0; hn1 = s1;
    } else {
        hn0 = hd0[t]; hn1 = hd1[t];
    }
    hs[t] = hn0; ht[t] = hn1;
    __syncthreads();

    {   // limit rows i = ch*32 + il (full dot over j)
        const int il = t >> 3, jc = t & 7;
        float L = 0.f;
#pragma unroll 8
        for (int jj = 0; jj < 32; ++jj) {
            const int j = jc + 8 * jj;
            L = fmaf(wsm[il * 264 + j], hs[j], L);
        }
        L += __shfl_down(L, 4);
        L += __shfl_down(L, 2);
        L += __shfl_down(L, 1);
        if (jc == 0) ws[OFF_PLIM + m * 256 + ch * 32 + il] = L;
    }
    {   // colimit partial
        float C = 0.f;
#pragma unroll 8
        for (int r = 0; r < 32; ++r)
            C = fmaf(wsm[r * 264 + t], ht[ch * 32 + r], C);
        ws[OFF_PCOL8 + blk * 256 + t] = C;
    }
}

// ---------------------------------------------------------------------------
// Out: single block -> avg_tension (out[128]).
// ---------------------------------------------------------------------------
__global__ __launch_bounds__(256) void k_out(const float* __restrict__ ws,
                                             float* __restrict__ out)
{
    __shared__ float red[256];
    const int t = threadIdx.x;
    float pt = 0.f;
    for (int i = t; i < 2048; i += 256) pt += ws[OFF_PT + i];
    float L = 0.f, C = 0.f;
    for (int m = 0; m < 32; ++m) L += ws[OFF_PLIM + m * 256 + t];
    for (int mc = 0; mc < 256; ++mc) C += ws[OFF_PCOL8 + mc * 256 + t];
    const float d = (L - C) * (1.f / 32.f);
    red[t] = d * d; __syncthreads();
    for (int s = 128; s > 0; s >>= 1) { if (t < s) red[t] += red[t + s]; __syncthreads(); }
    const float cat = red[0] * (1.f / 256.f); __syncthreads();
    red[t] = pt; __syncthreads();
    for (int s = 128; s > 0; s >>= 1) { if (t < s) red[t] += red[t + s]; __syncthreads(); }
    if (t == 0) out[128] = red[0] * (1.f / 65536.f) + 0.1f * cat;
}

// ---------------------------------------------------------------------------
extern "C" void kernel_launch(void* const* d_in, const int* in_sizes, int n_in,
                              void* d_out, int out_size, void* d_ws, size_t ws_size,
                              hipStream_t stream)
{
    const float* x     = (const float*)d_in[0];
    const float* hidd  = (const float*)d_in[1];
    const float* Wa1   = (const float*)d_in[2];
    const float* ba1   = (const float*)d_in[3];
    const float* Wa2   = (const float*)d_in[4];
    const float* ba2   = (const float*)d_in[5];
    const float* Wg1   = (const float*)d_in[6];
    const float* bg1   = (const float*)d_in[7];
    const float* Wg2   = (const float*)d_in[8];
    const float* bg2   = (const float*)d_in[9];
    const float* W_ih  = (const float*)d_in[10];
    const float* W_hh  = (const float*)d_in[11];
    const float* b_ih  = (const float*)d_in[12];
    const float* b_hh  = (const float*)d_in[13];
    const float* nat_w = (const float*)d_in[14];
    const float* mw    = (const float*)d_in[15];
    const int*   msrc  = (const int*)d_in[16];
    const int*   mtgt  = (const int*)d_in[17];
    const int*   step  = (const int*)d_in[18];

    float* out = (float*)d_out;
    float* ws  = (float*)d_ws;

    k_prep <<<322, 256, 0, stream>>>(x, hidd, Wa1, ba1, Wa2, ba2, Wg1, bg1, Wg2, bg2, msrc, mtgt, ws);
    k_main <<<2048, 256, 0, stream>>>(hidd, msrc, mtgt, ws);
    k_tail1<<<256, 256, 0, stream>>>(W_ih, W_hh, b_ih, b_hh, ws, out);
    k_morph<<<256, 256, 0, stream>>>(mw, nat_w, step, ws);
    k_out  <<<1, 256, 0, stream>>>(ws, out);
}